// Round 10
// baseline (108.388 us; speedup 1.0000x reference)
//
#include <hip/hip_runtime.h>
#include <hip/hip_bf16.h>
#include <math.h>

// Problem constants (fixed by the reference)
#define NPIX 256
#define HALF 128
#define NVIS 50000
#define TWO_PI_F 6.28318530717958647692f

// vis kernel geometry: 2 waves x 32 k's per block
#define VBLK 128
#define KPB  64
#define NBLK_VIS ((NVIS + KPB - 1) / KPB)   // 782 (covers 50048)

typedef __attribute__((ext_vector_type(8)))  short short8;
typedef __attribute__((ext_vector_type(16))) float f32x16;

__device__ __forceinline__ float cell_rad_f() {
    // match reference: jnp.float32(0.005) * np.float32(pi/180/3600)
    const float arcsec = (float)(M_PI / 180.0 / 3600.0);
    return 0.005f * arcsec;
}

__device__ __forceinline__ unsigned pack_bf2(float lo, float hi) {
    // 2x f32 -> packed bf16 pair (v_cvt_pk_bf16_f32)
    __hip_bfloat162 h = __float22bfloat162_rn(make_float2(lo, hi));
    return *reinterpret_cast<unsigned*>(&h);
}

// ---------------------------------------------------------------------------
// Prep: softplus + 3x3 Hann conv (math verified R3/R6/R8), emitted as bf16 in
// 32x32x16 A-fragment order:
//   wimg[((yt*16 + step)*64 + hv*32 + ycol)*8 + e]
// where y = yt*32 + ycol, x = step*16 + hv*8 + e.
// Grid: 32 blocks = (by 0..15: 16-row strip) x (xh 0..1: 128-col half).
// ---------------------------------------------------------------------------
#define SPR 18
#define SPC 130
__global__ __launch_bounds__(256) void prep_kernel(const float* __restrict__ base,
                                                   unsigned short* __restrict__ wimg) {
    __shared__ float sp[SPR][SPC];
    const int by = blockIdx.x >> 1, xh = blockIdx.x & 1;
    const int y0 = by * 16, x0 = xh * 128;
    const int tid = threadIdx.x;

    for (int idx = tid; idx < SPR * SPC; idx += 256) {
        int r = idx / SPC, c = idx - r * SPC;
        int y = y0 - 1 + r, x = x0 - 1 + c;
        float v = 0.f;
        if ((unsigned)y < NPIX && (unsigned)x < NPIX)
            v = log1pf(expf(base[y * NPIX + x]));
        sp[r][c] = v;
    }
    __syncthreads();

    // one conv octet per thread: yl = tid>>4 (row), oc = tid&15 (8-px column run)
    {
        int yl = tid >> 4, oc = tid & 15;
        union { unsigned short u[8]; uint4 v; } pk;
        #pragma unroll
        for (int e = 0; e < 8; ++e) {
            int cl = oc * 8 + e;     // sp col of conv-center-minus-1
            float top = sp[yl    ][cl] + 2.f * sp[yl    ][cl + 1] + sp[yl    ][cl + 2];
            float mid = sp[yl + 1][cl] + 2.f * sp[yl + 1][cl + 1] + sp[yl + 1][cl + 2];
            float bot = sp[yl + 2][cl] + 2.f * sp[yl + 2][cl + 1] + sp[yl + 2][cl + 2];
            float cv  = 0.0625f * (top + 2.f * mid + bot);
            __hip_bfloat16 h = __float2bfloat16(cv);
            pk.u[e] = *reinterpret_cast<unsigned short*>(&h);
        }
        int gx   = x0 + oc * 8;          // global x of first px
        int step = gx >> 4, hv = (gx >> 3) & 1;
        int y    = y0 + yl;
        int yt   = y >> 5, ycol = y & 31;
        size_t off = (((size_t)yt * 16 + step) * 64 + hv * 32 + ycol) * 8;
        *(uint4*)(wimg + off) = pk.v;
    }
}

// ---------------------------------------------------------------------------
// Vis: 32x32x16 bf16 MFMA NUDFT, operands swapped (A = image, B = phase).
//   T[y,k] = sum_x img[y,x] * a_k(x),  a_k = exp(-i*del_k*(x-128))
//   vis[k] = sum_y T[y,k] * exp(-i*eps_k*(y-128)) * cell^2
// A (M=32 y, K=16 x): row=lane&31, K-elem=(lane>>5)*8+e  [from LDS]
// B (K=16, N=32 k):  col=lane&31, K-elem=(lane>>5)*8+e  [registers, 32x short8]
// C/D: col=lane&31 (k), row=(r&3)+8*(r>>2)+4*(lane>>5) (y)  [HW-verified m74/m101]
// => each lane owns ONE k; epilogue b-rotation is 2 regs; reduce = 1 shfl_xor(32).
// Output planar f32 [re-plane][im-plane] (verified R6).
// ---------------------------------------------------------------------------
__global__ __launch_bounds__(VBLK) void vis_mfma(const float* __restrict__ uu,
                                                 const float* __restrict__ vv,
                                                 const unsigned short* __restrict__ wimg,
                                                 float* __restrict__ out) {
    __shared__ uint4 lds4[2048];                  // 32 KB = 2 y-tiles of fragments
    unsigned short* lds = (unsigned short*)lds4;

    const int tid  = threadIdx.x;
    const int wid  = tid >> 6, lane = tid & 63;
    const int kcol = lane & 31, hv = lane >> 5;
    const int k0   = blockIdx.x * KPB + wid * 32;

    const float cell = cell_rad_f();
    const float sc   = TWO_PI_F * 1e3f * cell;

    int ka = k0 + kcol; if (ka > NVIS - 1) ka = NVIS - 1;
    const float del = sc * uu[ka];
    const float eps = sc * vv[ka];

    // --- B phase fragments: x = step*16 + hv*8 + e, value exp(-i*del*(x-128)) ---
    float cd, sd; sincosf(del, &sd, &cd);            // rot1x = (cd, -sd)
    float c16, s16; sincosf(16.f * del, &s16, &c16); // rot16x = (c16, -s16)
    float th0 = del * (float)(hv * 8 - HALF);
    float s0, c0; sincosf(th0, &s0, &c0);
    float bar = c0, bai = -s0;                       // step-base a = exp(-i*th0)

    union BF { short8 v; unsigned u[4]; };
    BF Bre[16], Bim[16];
    #pragma unroll
    for (int step = 0; step < 16; ++step) {
        float ar = bar, ai = bai;
        #pragma unroll
        for (int ep = 0; ep < 4; ++ep) {
            float ar1 = fmaf(ar, cd,  ai * sd);      // *= exp(-i*del)
            float ai1 = fmaf(ai, cd, -ar * sd);
            Bre[step].u[ep] = pack_bf2(ar, ar1);
            Bim[step].u[ep] = pack_bf2(ai, ai1);
            ar = fmaf(ar1, cd,  ai1 * sd);
            ai = fmaf(ai1, cd, -ar1 * sd);
        }
        float nbr = fmaf(bar, c16,  bai * s16);      // base *= exp(-i*16*del)
        float nbi = fmaf(bai, c16, -bar * s16);
        bar = nbr; bai = nbi;
    }

    // --- y-rotations: rot1y = exp(-i*eps); rot8y = rot1y^8 by squaring ---
    float ce, se; sincosf(eps, &se, &ce);
    const float r1r = ce, r1i = -se;
    float r2r = fmaf(r1r, r1r, -r1i * r1i), r2i = 2.f * r1r * r1i;
    float r4r = fmaf(r2r, r2r, -r2i * r2i), r4i = 2.f * r2r * r2i;
    float r8r = fmaf(r4r, r4r, -r4i * r4i), r8i = 2.f * r4r * r4i;

    float visr = 0.f, visi = 0.f;

    for (int p = 0; p < 4; ++p) {
        __syncthreads();
        const uint4* src = (const uint4*)wimg + (size_t)p * 2048;
        #pragma unroll
        for (int i = 0; i < 16; ++i) lds4[i * VBLK + tid] = src[i * VBLK + tid];
        __syncthreads();

        #pragma unroll
        for (int t = 0; t < 2; ++t) {
            f32x16 aR = {0.f}, aI = {0.f};
            #pragma unroll
            for (int i = 1; i < 16; ++i) { aR[i] = 0.f; aI[i] = 0.f; }
            #pragma unroll
            for (int step = 0; step < 16; ++step) {
                short8 A = *(const short8*)&lds[(((t * 16 + step) * 64) + lane) * 8];
                aR = __builtin_amdgcn_mfma_f32_32x32x16_bf16(A, Bre[step].v, aR, 0, 0, 0);
                aI = __builtin_amdgcn_mfma_f32_32x32x16_bf16(A, Bim[step].v, aI, 0, 0, 0);
            }
            // epilogue: lane's y for reg r = Y0 + 4*hv + (r&3) + 8*(r>>2)
            const int Y0 = (p * 2 + t) * 32;
            float w0 = eps * (float)(Y0 + 4 * hv - HALF);
            float sw, cw; sincosf(w0, &sw, &cw);
            float bgr = cw, bgi = -sw;               // group base b
            #pragma unroll
            for (int grp = 0; grp < 4; ++grp) {
                float br_ = bgr, bi_ = bgi;
                #pragma unroll
                for (int j = 0; j < 4; ++j) {
                    int r = grp * 4 + j;
                    // vis += T*b: re += TR*br - TI*bi ; im += TI*br + TR*bi
                    visr = fmaf(aR[r], br_, visr); visr = fmaf(-aI[r], bi_, visr);
                    visi = fmaf(aI[r], br_, visi); visi = fmaf( aR[r], bi_, visi);
                    float nr = fmaf(br_, r1r, -bi_ * r1i);   // b *= rot1y
                    float ni = fmaf(bi_, r1r,  br_ * r1i);
                    br_ = nr; bi_ = ni;
                }
                float ngr = fmaf(bgr, r8r, -bgi * r8i);      // base *= rot8y
                float ngi = fmaf(bgi, r8r,  bgr * r8i);
                bgr = ngr; bgi = ngi;
            }
        }
    }

    // combine the two hv-halves (y-coverage split): lane L <-> L+32 share k
    visr += __shfl_xor(visr, 32);
    visi += __shfl_xor(visi, 32);

    if (hv == 0) {
        int kk = k0 + kcol;
        if (kk < NVIS) {
            const float c2 = cell * cell;
            out[kk]        = visr * c2;   // real plane
            out[NVIS + kk] = visi * c2;   // imag plane
        }
    }
}

extern "C" void kernel_launch(void* const* d_in, const int* in_sizes, int n_in,
                              void* d_out, int out_size, void* d_ws, size_t ws_size,
                              hipStream_t stream) {
    const float* base = (const float*)d_in[0];   // (1,256,256) f32
    const float* uu   = (const float*)d_in[1];   // (50000,) f32
    const float* vv   = (const float*)d_in[2];   // (50000,) f32
    (void)in_sizes; (void)n_in; (void)out_size; (void)ws_size;

    unsigned short* wimg = (unsigned short*)d_ws;    // 128 KB fragment-ordered bf16 image

    prep_kernel<<<32, 256, 0, stream>>>(base, wimg);
    vis_mfma<<<NBLK_VIS, VBLK, 0, stream>>>(uu, vv, wimg, (float*)d_out);
}

// Round 11
// 101.102 us; speedup vs baseline: 1.0721x; 1.0721x over previous
//
#include <hip/hip_runtime.h>
#include <hip/hip_bf16.h>
#include <math.h>

// Problem constants (fixed by the reference)
#define NPIX 256
#define HALF 128
#define NVIS 50000
#define TWO_PI_F 6.28318530717958647692f

// vis kernel geometry: 2 waves x 32 k's per block
#define VBLK 128
#define KPB  64
#define NBLK_VIS ((NVIS + KPB - 1) / KPB)   // 782 (covers 50048)

typedef __attribute__((ext_vector_type(8)))  short short8;
typedef __attribute__((ext_vector_type(16))) float f32x16;

__device__ __forceinline__ float cell_rad_f() {
    // match reference: jnp.float32(0.005) * np.float32(pi/180/3600)
    const float arcsec = (float)(M_PI / 180.0 / 3600.0);
    return 0.005f * arcsec;
}

__device__ __forceinline__ unsigned pack_bf2(float lo, float hi) {
    // 2x f32 -> packed bf16 pair (v_cvt_pk_bf16_f32)
    __hip_bfloat162 h = __float22bfloat162_rn(make_float2(lo, hi));
    return *reinterpret_cast<unsigned*>(&h);
}

// ---------------------------------------------------------------------------
// Prep: softplus + 3x3 Hann conv (math verified R3/R6/R8), emitted as bf16 in
// 32x32x16 A-fragment order:
//   wimg[((yt*16 + step)*64 + hv*32 + ycol)*8 + e]
// where y = yt*32 + ycol, x = step*16 + hv*8 + e.
// Grid: 32 blocks = (by 0..15: 16-row strip) x (xh 0..1: 128-col half).
// ---------------------------------------------------------------------------
#define SPR 18
#define SPC 130
__global__ __launch_bounds__(256) void prep_kernel(const float* __restrict__ base,
                                                   unsigned short* __restrict__ wimg) {
    __shared__ float sp[SPR][SPC];
    const int by = blockIdx.x >> 1, xh = blockIdx.x & 1;
    const int y0 = by * 16, x0 = xh * 128;
    const int tid = threadIdx.x;

    for (int idx = tid; idx < SPR * SPC; idx += 256) {
        int r = idx / SPC, c = idx - r * SPC;
        int y = y0 - 1 + r, x = x0 - 1 + c;
        float v = 0.f;
        if ((unsigned)y < NPIX && (unsigned)x < NPIX)
            v = log1pf(expf(base[y * NPIX + x]));
        sp[r][c] = v;
    }
    __syncthreads();

    // one conv octet per thread: yl = tid>>4 (row), oc = tid&15 (8-px column run)
    {
        int yl = tid >> 4, oc = tid & 15;
        union { unsigned short u[8]; uint4 v; } pk;
        #pragma unroll
        for (int e = 0; e < 8; ++e) {
            int cl = oc * 8 + e;     // sp col of conv-center-minus-1
            float top = sp[yl    ][cl] + 2.f * sp[yl    ][cl + 1] + sp[yl    ][cl + 2];
            float mid = sp[yl + 1][cl] + 2.f * sp[yl + 1][cl + 1] + sp[yl + 1][cl + 2];
            float bot = sp[yl + 2][cl] + 2.f * sp[yl + 2][cl + 1] + sp[yl + 2][cl + 2];
            float cv  = 0.0625f * (top + 2.f * mid + bot);
            __hip_bfloat16 h = __float2bfloat16(cv);
            pk.u[e] = *reinterpret_cast<unsigned short*>(&h);
        }
        int gx   = x0 + oc * 8;          // global x of first px
        int step = gx >> 4, hv = (gx >> 3) & 1;
        int y    = y0 + yl;
        int yt   = y >> 5, ycol = y & 31;
        size_t off = (((size_t)yt * 16 + step) * 64 + hv * 32 + ycol) * 8;
        *(uint4*)(wimg + off) = pk.v;
    }
}

// ---------------------------------------------------------------------------
// Vis: 32x32x16 bf16 MFMA NUDFT, operands swapped (A = image, B = phase).
//   T[y,k] = sum_x img[y,x] * a_k(x),  a_k = exp(-i*del_k*(x-128))
//   vis[k] = sum_y T[y,k] * exp(-i*eps_k*(y-128)) * cell^2
// A (M=32 y, K=16 x): row=lane&31, K-elem=(lane>>5)*8+e  [DIRECT from global:
//   wimg is 128KB, L2-resident; LDS staging was the R10 latency bound]
// B (K=16, N=32 k):  col=lane&31, K-elem=(lane>>5)*8+e  [registers, 32x short8]
// C/D: col=lane&31 (k), row=(r&3)+8*(r>>2)+4*(lane>>5) (y)  [HW-verified]
// No LDS, no barriers: waves run independently; 2-deep group prefetch per yt.
// Output planar f32 [re-plane][im-plane] (verified R6).
// ---------------------------------------------------------------------------
__global__ __launch_bounds__(VBLK) void vis_mfma(const float* __restrict__ uu,
                                                 const float* __restrict__ vv,
                                                 const unsigned short* __restrict__ wimg,
                                                 float* __restrict__ out) {
    const int tid  = threadIdx.x;
    const int wid  = tid >> 6, lane = tid & 63;
    const int kcol = lane & 31, hv = lane >> 5;
    const int k0   = blockIdx.x * KPB + wid * 32;

    const float cell = cell_rad_f();
    const float sc   = TWO_PI_F * 1e3f * cell;

    int ka = k0 + kcol; if (ka > NVIS - 1) ka = NVIS - 1;
    const float del = sc * uu[ka];
    const float eps = sc * vv[ka];

    // --- B phase fragments: x = step*16 + hv*8 + e, value exp(-i*del*(x-128)) ---
    float cd, sd; sincosf(del, &sd, &cd);            // rot1x = (cd, -sd)
    float c16, s16; sincosf(16.f * del, &s16, &c16); // rot16x = (c16, -s16)
    float th0 = del * (float)(hv * 8 - HALF);
    float s0, c0; sincosf(th0, &s0, &c0);
    float bar = c0, bai = -s0;                       // step-base a = exp(-i*th0)

    union BF { short8 v; unsigned u[4]; };
    BF Bre[16], Bim[16];
    #pragma unroll
    for (int step = 0; step < 16; ++step) {
        float ar = bar, ai = bai;
        #pragma unroll
        for (int ep = 0; ep < 4; ++ep) {
            float ar1 = fmaf(ar, cd,  ai * sd);      // *= exp(-i*del)
            float ai1 = fmaf(ai, cd, -ar * sd);
            Bre[step].u[ep] = pack_bf2(ar, ar1);
            Bim[step].u[ep] = pack_bf2(ai, ai1);
            ar = fmaf(ar1, cd,  ai1 * sd);
            ai = fmaf(ai1, cd, -ar1 * sd);
        }
        float nbr = fmaf(bar, c16,  bai * s16);      // base *= exp(-i*16*del)
        float nbi = fmaf(bai, c16, -bar * s16);
        bar = nbr; bai = nbi;
    }

    // --- y-rotations: rot1y = exp(-i*eps); rot8y = rot1y^8 by squaring ---
    float ce, se; sincosf(eps, &se, &ce);
    const float r1r = ce, r1i = -se;
    float r2r = fmaf(r1r, r1r, -r1i * r1i), r2i = 2.f * r1r * r1i;
    float r4r = fmaf(r2r, r2r, -r2i * r2i), r4i = 2.f * r2r * r2i;
    float r8r = fmaf(r4r, r4r, -r4i * r4i), r8i = 2.f * r4r * r4i;

    float visr = 0.f, visi = 0.f;

    const short8* __restrict__ Afrag = (const short8*)wimg;  // frag idx = (yt*16+step)*64+lane

    #pragma unroll 2
    for (int yt = 0; yt < 8; ++yt) {
        f32x16 aR, aI;
        #pragma unroll
        for (int i = 0; i < 16; ++i) { aR[i] = 0.f; aI[i] = 0.f; }

        const int fb = yt * 16;
        short8 A0[4], A1[4];
        #pragma unroll
        for (int j = 0; j < 4; ++j) A0[j] = Afrag[(fb + j) * 64 + lane];

        #pragma unroll
        for (int g = 0; g < 4; ++g) {
            // prefetch next group into the alternate buffer (static after unroll)
            if (g < 3) {
                #pragma unroll
                for (int j = 0; j < 4; ++j) {
                    if (g & 1) A0[j] = Afrag[(fb + (g + 1) * 4 + j) * 64 + lane];
                    else       A1[j] = Afrag[(fb + (g + 1) * 4 + j) * 64 + lane];
                }
            }
            #pragma unroll
            for (int j = 0; j < 4; ++j) {
                const short8 A = (g & 1) ? A1[j] : A0[j];
                aR = __builtin_amdgcn_mfma_f32_32x32x16_bf16(A, Bre[g * 4 + j].v, aR, 0, 0, 0);
                aI = __builtin_amdgcn_mfma_f32_32x32x16_bf16(A, Bim[g * 4 + j].v, aI, 0, 0, 0);
            }
        }

        // epilogue: lane's y for reg r = yt*32 + 4*hv + (r&3) + 8*(r>>2)
        float w0 = eps * (float)(yt * 32 + 4 * hv - HALF);
        float sw, cw; sincosf(w0, &sw, &cw);
        float bgr = cw, bgi = -sw;               // group base b
        #pragma unroll
        for (int grp = 0; grp < 4; ++grp) {
            float br_ = bgr, bi_ = bgi;
            #pragma unroll
            for (int j = 0; j < 4; ++j) {
                int r = grp * 4 + j;
                // vis += T*b: re += TR*br - TI*bi ; im += TI*br + TR*bi
                visr = fmaf(aR[r], br_, visr); visr = fmaf(-aI[r], bi_, visr);
                visi = fmaf(aI[r], br_, visi); visi = fmaf( aR[r], bi_, visi);
                float nr = fmaf(br_, r1r, -bi_ * r1i);   // b *= rot1y
                float ni = fmaf(bi_, r1r,  br_ * r1i);
                br_ = nr; bi_ = ni;
            }
            float ngr = fmaf(bgr, r8r, -bgi * r8i);      // base *= rot8y
            float ngi = fmaf(bgi, r8r,  bgr * r8i);
            bgr = ngr; bgi = ngi;
        }
    }

    // combine the two hv-halves (complementary y-sets): lane L <-> L+32 share k
    visr += __shfl_xor(visr, 32);
    visi += __shfl_xor(visi, 32);

    if (hv == 0) {
        int kk = k0 + kcol;
        if (kk < NVIS) {
            const float c2 = cell * cell;
            out[kk]        = visr * c2;   // real plane
            out[NVIS + kk] = visi * c2;   // imag plane
        }
    }
}

extern "C" void kernel_launch(void* const* d_in, const int* in_sizes, int n_in,
                              void* d_out, int out_size, void* d_ws, size_t ws_size,
                              hipStream_t stream) {
    const float* base = (const float*)d_in[0];   // (1,256,256) f32
    const float* uu   = (const float*)d_in[1];   // (50000,) f32
    const float* vv   = (const float*)d_in[2];   // (50000,) f32
    (void)in_sizes; (void)n_in; (void)out_size; (void)ws_size;

    unsigned short* wimg = (unsigned short*)d_ws;    // 128 KB fragment-ordered bf16 image

    prep_kernel<<<32, 256, 0, stream>>>(base, wimg);
    vis_mfma<<<NBLK_VIS, VBLK, 0, stream>>>(uu, vv, wimg, (float*)d_out);
}